// Round 3
// baseline (474.280 us; speedup 1.0000x reference)
//
#include <hip/hip_runtime.h>
#include <hip/hip_bf16.h>

typedef _Float16 half_t;
typedef _Float16 f16x8 __attribute__((ext_vector_type(8)));
typedef _Float16 f16x4 __attribute__((ext_vector_type(4)));
typedef float f32x4 __attribute__((ext_vector_type(4)));

#define B_ROWS 8192
#define D_DIM  1024

__device__ __forceinline__ void gload_lds16(const void* g, void* l)
{
    __builtin_amdgcn_global_load_lds((const __attribute__((address_space(1))) void*)g,
                                     (__attribute__((address_space(3))) void*)l, 16, 0, 0);
}

// ---------------------------------------------------------------------------
// f32 -> f16 convert
// ---------------------------------------------------------------------------
__global__ __launch_bounds__(256)
void cvt_f32_f16(const float* __restrict__ in, half_t* __restrict__ out, int n)
{
    int i = (blockIdx.x * 256 + threadIdx.x) * 4;
    int stride = gridDim.x * 256 * 4;
    for (; i < n; i += stride) {
        float4 v = *(const float4*)&in[i];
        f16x4 o;
        o[0] = (half_t)v.x; o[1] = (half_t)v.y; o[2] = (half_t)v.z; o[3] = (half_t)v.w;
        *(f16x4*)&out[i] = o;
    }
}

// ---------------------------------------------------------------------------
// LDS-tiled transpose (64x64 tiles, +1 pad)
// ---------------------------------------------------------------------------
__global__ __launch_bounds__(256)
void transpose_h(const half_t* __restrict__ in, half_t* __restrict__ out, int R, int C)
{
    __shared__ half_t t[64][65];
    int tilesC = C >> 6;
    int bc = blockIdx.x % tilesC;
    int br = blockIdx.x / tilesC;
    int r0 = br * 64, c0 = bc * 64;
    for (int e = threadIdx.x; e < 64 * 64; e += 256) {
        int r = e >> 6, c = e & 63;
        t[r][c] = in[(size_t)(r0 + r) * C + (c0 + c)];
    }
    __syncthreads();
    for (int e = threadIdx.x; e < 64 * 64; e += 256) {
        int r = e >> 6, c = e & 63;
        out[(size_t)(c0 + r) * R + (r0 + c)] = t[c][r];
    }
}

// ---------------------------------------------------------------------------
// 256x256 NT GEMM, 4-region pipelined schedule (v3).
//   C[i,j] = scale * sum_k A[i,k]*B[j,k] (+bias[j])
// 512 threads = 8 waves (2Mx4N). LDS 128 KiB (2 dbuf x 2 halves x A,B).
// Per K-tile t: 4 regions, ONE barrier each; frag reads pipelined one region
// ahead so ds_read overlaps MFMA; B-frags (bfP=B0, bfQ=B1) persist across the
// phase pair (24 instead of 32 ds_read_b128 per wave per K-tile).
//   R1: vmcnt(4) gate{A1,B1(t)}; bar; stage A1(t+1); read bfQ<-B1(t);  MFMA p1 = afA(A0,t) x bfP -> acc[0..3][0..1]
//   R2:                          bar; stage B1(t+1); read afN<-A1(t);  MFMA p2 = afA x bfQ        -> acc[0..3][2..3]
//   R3: vmcnt(4) gate{A0,B0(t+1)};bar; stage A0(t+2); read afA<-A0(t+1);MFMA p3 = afN(A1,t) x bfP -> acc[4..7][0..1]
//   R4:                          bar; stage B0(t+2); read bfP<-B0(t+1);MFMA p4 = afN x bfQ        -> acc[4..7][2..3]
// WAR: every stage's target buffer had its last reader >=1 barrier earlier.
// RAW: every read of staged data is preceded by a covering vmcnt gate+barrier.
// ---------------------------------------------------------------------------
template<int EPI>
__device__ __forceinline__ void gemm8_core(
    const half_t* __restrict__ A, const half_t* __restrict__ Bm,
    const float* __restrict__ bias, void* __restrict__ Out,
    int lda, int ldb, int ldc, float scale,
    int row0, int col0, int ktile0, int nkt)
{
    __shared__ __align__(16) half_t As[4 * 8192];
    __shared__ __align__(16) half_t Bs[4 * 8192];

    const int tid  = threadIdx.x;
    const int lane = tid & 63;
    const int wid  = tid >> 6;
    const int wr   = wid >> 2;     // 0..1  (M)
    const int wcn  = wid & 3;      // 0..3  (N)
    const int l15  = lane & 15;
    const int l4   = lane >> 4;

    // staging: linear LDS dest (tid*16), inverse-swizzled global source slot
    const int trow  = tid >> 3;                       // 0..63
    const int tslot = (tid & 7) ^ (trow & 7);
    const char* Apan[2] = { (const char*)(A + (size_t)row0 * lda),
                            (const char*)(A + (size_t)(row0 + 128) * lda) };
    const char* Bpan[2] = { (const char*)(Bm + (size_t)col0 * ldb),
                            (const char*)(Bm + (size_t)(col0 + 128) * ldb) };
    const int aoff[2] = { trow * lda * 2 + tslot * 16, (trow + 64) * lda * 2 + tslot * 16 };
    const int boff[2] = { trow * ldb * 2 + tslot * 16, (trow + 64) * ldb * 2 + tslot * 16 };
    const int dstb[2] = { tid * 16, 8192 + tid * 16 };

    auto stageA = [&](int h, int s, int buf) {
        char* d = (char*)(As + (buf * 2 + h) * 8192);
        const char* g = Apan[h] + (size_t)(ktile0 + s) * 128;
        gload_lds16(g + aoff[0], d + dstb[0]);
        gload_lds16(g + aoff[1], d + dstb[1]);
    };
    auto stageB = [&](int h, int s, int buf) {
        char* d = (char*)(Bs + (buf * 2 + h) * 8192);
        const char* g = Bpan[h] + (size_t)(ktile0 + s) * 128;
        gload_lds16(g + boff[0], d + dstb[0]);
        gload_lds16(g + boff[1], d + dstb[1]);
    };
    // swizzled fragment reads
    auto rdA = [&](int mm, int kb, const half_t* base) -> f16x8 {
        int rih  = mm * 32 + wr * 16 + l15;
        int byte = rih * 128 + (((kb * 4 + l4) ^ (rih & 7)) << 4);
        return *(const f16x8*)((const char*)base + byte);
    };
    auto rdB = [&](int nn, int kb, const half_t* base) -> f16x8 {
        int rih  = nn * 64 + wcn * 16 + l15;
        int byte = rih * 128 + (((kb * 4 + l4) ^ (rih & 7)) << 4);
        return *(const f16x8*)((const char*)base + byte);
    };

    f32x4 acc[8][4] = {};
    f16x8 afA[4][2];   // A-frags, ping (A0 of t in R1-2, A0 of t+1 after R3)
    f16x8 afN[4][2];   // A-frags, pong (A1 of t)
    f16x8 bfP[2][2];   // B0 frags (persist p1 & p3)
    f16x8 bfQ[2][2];   // B1 frags (persist p2 & p4)

    // prologue: stage tile0 fully + A0/B0 of tile1; land tile0 A0/B0; read p1 frags
    {
        int s1 = (nkt > 1) ? 1 : 0;
        stageA(0, 0, 0); stageB(0, 0, 0); stageA(1, 0, 0); stageB(1, 0, 0);
        stageA(0, s1, 1); stageB(0, s1, 1);
    }
    asm volatile("s_waitcnt vmcnt(8)" ::: "memory");
    asm volatile("s_barrier" ::: "memory");
    {
        const half_t* A0 = As;
        const half_t* B0 = Bs;
        #pragma unroll
        for (int m = 0; m < 4; ++m) { afA[m][0] = rdA(m, 0, A0); afA[m][1] = rdA(m, 1, A0); }
        #pragma unroll
        for (int n = 0; n < 2; ++n) { bfP[n][0] = rdB(n, 0, B0); bfP[n][1] = rdB(n, 1, B0); }
    }

    for (int t = 0; t < nkt; ++t) {
        const int buf = t & 1;
        const int b1  = buf ^ 1;
        const half_t* A1c = As + (buf * 2 + 1) * 8192;
        const half_t* B1c = Bs + (buf * 2 + 1) * 8192;
        const half_t* A0n = As + (b1 * 2 + 0) * 8192;
        const half_t* B0n = Bs + (b1 * 2 + 0) * 8192;
        int t1s = (t + 1 < nkt) ? t + 1 : nkt - 1;
        int t2s = (t + 2 < nkt) ? t + 2 : nkt - 1;

        // ---- R1
        asm volatile("s_waitcnt vmcnt(4)" ::: "memory");
        asm volatile("s_barrier" ::: "memory");
        stageA(1, t1s, b1);
        #pragma unroll
        for (int n = 0; n < 2; ++n) { bfQ[n][0] = rdB(n, 0, B1c); bfQ[n][1] = rdB(n, 1, B1c); }
        __builtin_amdgcn_s_setprio(1);
        #pragma unroll
        for (int kb = 0; kb < 2; ++kb)
            #pragma unroll
            for (int m = 0; m < 4; ++m)
                #pragma unroll
                for (int n = 0; n < 2; ++n)
                    acc[m][n] = __builtin_amdgcn_mfma_f32_16x16x32_f16(afA[m][kb], bfP[n][kb], acc[m][n], 0, 0, 0);
        __builtin_amdgcn_s_setprio(0);

        // ---- R2
        asm volatile("s_barrier" ::: "memory");
        stageB(1, t1s, b1);
        #pragma unroll
        for (int m = 0; m < 4; ++m) { afN[m][0] = rdA(m, 0, A1c); afN[m][1] = rdA(m, 1, A1c); }
        __builtin_amdgcn_s_setprio(1);
        #pragma unroll
        for (int kb = 0; kb < 2; ++kb)
            #pragma unroll
            for (int m = 0; m < 4; ++m)
                #pragma unroll
                for (int n = 0; n < 2; ++n)
                    acc[m][n + 2] = __builtin_amdgcn_mfma_f32_16x16x32_f16(afA[m][kb], bfQ[n][kb], acc[m][n + 2], 0, 0, 0);
        __builtin_amdgcn_s_setprio(0);

        // ---- R3
        asm volatile("s_waitcnt vmcnt(4)" ::: "memory");
        asm volatile("s_barrier" ::: "memory");
        stageA(0, t2s, buf);
        #pragma unroll
        for (int m = 0; m < 4; ++m) { afA[m][0] = rdA(m, 0, A0n); afA[m][1] = rdA(m, 1, A0n); }
        __builtin_amdgcn_s_setprio(1);
        #pragma unroll
        for (int kb = 0; kb < 2; ++kb)
            #pragma unroll
            for (int m = 0; m < 4; ++m)
                #pragma unroll
                for (int n = 0; n < 2; ++n)
                    acc[m + 4][n] = __builtin_amdgcn_mfma_f32_16x16x32_f16(afN[m][kb], bfP[n][kb], acc[m + 4][n], 0, 0, 0);
        __builtin_amdgcn_s_setprio(0);

        // ---- R4
        asm volatile("s_barrier" ::: "memory");
        stageB(0, t2s, buf);
        #pragma unroll
        for (int n = 0; n < 2; ++n) { bfP[n][0] = rdB(n, 0, B0n); bfP[n][1] = rdB(n, 1, B0n); }
        __builtin_amdgcn_s_setprio(1);
        #pragma unroll
        for (int kb = 0; kb < 2; ++kb)
            #pragma unroll
            for (int m = 0; m < 4; ++m)
                #pragma unroll
                for (int n = 0; n < 2; ++n)
                    acc[m + 4][n + 2] = __builtin_amdgcn_mfma_f32_16x16x32_f16(afN[m][kb], bfQ[n][kb], acc[m + 4][n + 2], 0, 0, 0);
        __builtin_amdgcn_s_setprio(0);
    }

    // epilogue: C/D layout col = l15, row = l4*4 + r
    #pragma unroll
    for (int m = 0; m < 8; ++m) {
        int grow_base = row0 + m * 32 + wr * 16 + l4 * 4;
        #pragma unroll
        for (int n = 0; n < 4; ++n) {
            int gcol = col0 + n * 64 + wcn * 16 + l15;
            float badd = (EPI == 0) ? bias[gcol] : 0.0f;
            #pragma unroll
            for (int r = 0; r < 4; ++r) {
                float v = acc[m][n][r] * scale + badd;
                size_t idx = (size_t)(grow_base + r) * ldc + gcol;
                if (EPI == 2) ((float*)Out)[idx] = v;
                else          ((half_t*)Out)[idx] = (half_t)v;
            }
        }
    }
}

// generic wrapper (XCD swizzle when grid divisible by 8)
template<int EPI>
__global__ __launch_bounds__(512, 2)
void gemm8(const half_t* __restrict__ A, const half_t* __restrict__ Bm,
           const float* __restrict__ bias, void* __restrict__ Out,
           int lda, int ldb, int ldc, float scale, int nkt)
{
    int nwg = gridDim.x * gridDim.y;
    int bid = blockIdx.y * gridDim.x + blockIdx.x;
    if ((nwg & 7) == 0) { int c = nwg >> 3; bid = (bid & 7) * c + (bid >> 3); }
    int bx = bid % gridDim.x, by = bid / gridDim.x;
    gemm8_core<EPI>(A, Bm, bias, Out, lda, ldb, ldc, scale, by * 256, bx * 256, 0, nkt);
}

// fused QKV projections: z picks (W, b, Out)
__global__ __launch_bounds__(512, 2)
void gemm8_qkv(const half_t* __restrict__ xh,
               const half_t* __restrict__ Wq, const half_t* __restrict__ Wk, const half_t* __restrict__ Wv,
               const float* __restrict__ bq, const float* __restrict__ bk, const float* __restrict__ bv,
               half_t* __restrict__ Q, half_t* __restrict__ K, half_t* __restrict__ V)
{
    int z = blockIdx.z;
    const half_t* W = (z == 0) ? Wq : (z == 1) ? Wk : Wv;
    const float*  b = (z == 0) ? bq : (z == 1) ? bk : bv;
    half_t*       O = (z == 0) ? Q  : (z == 1) ? K  : V;
    gemm8_core<0>(xh, W, b, O, D_DIM, D_DIM, D_DIM, 1.0f,
                  blockIdx.y * 256, blockIdx.x * 256, 0, D_DIM / 64);
}

// PV with split-K=2: z=0 -> part0 (d_out), z=1 -> part1 (ws)
__global__ __launch_bounds__(512, 2)
void gemm8_pv(const half_t* __restrict__ S, const half_t* __restrict__ Vt,
              float* __restrict__ part0, float* __restrict__ part1)
{
    int z = blockIdx.z;
    float* O = z ? part1 : part0;
    gemm8_core<2>(S, Vt, nullptr, O, B_ROWS, B_ROWS, D_DIM, 1.0f,
                  blockIdx.y * 256, blockIdx.x * 256, z * (B_ROWS / 128), B_ROWS / 128);
}

// out += a
__global__ __launch_bounds__(256)
void add_f32(const float* __restrict__ a, float* __restrict__ out, int n)
{
    int i = (blockIdx.x * 256 + threadIdx.x) * 4;
    int stride = gridDim.x * 256 * 4;
    for (; i < n; i += stride) {
        float4 x = *(const float4*)&out[i];
        float4 y = *(const float4*)&a[i];
        x.x += y.x; x.y += y.y; x.z += y.z; x.w += y.w;
        *(float4*)&out[i] = x;
    }
}

// ---------------------------------------------------------------------------
// Row softmax in place on fp16 [8192 x 8192]
// ---------------------------------------------------------------------------
__global__ __launch_bounds__(256)
void softmax_rows(half_t* __restrict__ S, int ncol)
{
    const int row = blockIdx.x;
    half_t* srow = S + (size_t)row * ncol;
    const int tid = threadIdx.x;

    float ev[32];
    float m = -1e30f;
    #pragma unroll
    for (int it = 0; it < 4; ++it) {
        int j = it * 2048 + tid * 8;
        f16x8 v = *(const f16x8*)&srow[j];
        #pragma unroll
        for (int t = 0; t < 8; ++t) {
            float f = (float)v[t];
            ev[it * 8 + t] = f;
            m = fmaxf(m, f);
        }
    }
    #pragma unroll
    for (int o = 32; o; o >>= 1) m = fmaxf(m, __shfl_down(m, o));
    __shared__ float redm[8];
    __shared__ float reds[8];
    if ((tid & 63) == 0) redm[tid >> 6] = m;
    __syncthreads();
    m = fmaxf(fmaxf(redm[0], redm[1]), fmaxf(redm[2], redm[3]));

    float s = 0.0f;
    #pragma unroll
    for (int e = 0; e < 32; ++e) {
        float ex = __expf(ev[e] - m);
        ev[e] = ex;
        s += ex;
    }
    #pragma unroll
    for (int o = 32; o; o >>= 1) s += __shfl_down(s, o);
    if ((tid & 63) == 0) reds[tid >> 6] = s;
    __syncthreads();
    s = reds[0] + reds[1] + reds[2] + reds[3];
    float inv = 1.0f / s;

    #pragma unroll
    for (int it = 0; it < 4; ++it) {
        int j = it * 2048 + tid * 8;
        f16x8 o8;
        #pragma unroll
        for (int t = 0; t < 8; ++t) o8[t] = (half_t)(ev[it * 8 + t] * inv);
        *(f16x8*)&srow[j] = o8;
    }
}

// ---------------------------------------------------------------------------
// launcher
// ---------------------------------------------------------------------------
extern "C" void kernel_launch(void* const* d_in, const int* in_sizes, int n_in,
                              void* d_out, int out_size, void* d_ws, size_t ws_size,
                              hipStream_t stream)
{
    const float* x  = (const float*)d_in[0];
    const float* Wq = (const float*)d_in[1];
    const float* bq = (const float*)d_in[2];
    const float* Wk = (const float*)d_in[3];
    const float* bk = (const float*)d_in[4];
    const float* Wv = (const float*)d_in[5];
    const float* bv = (const float*)d_in[6];
    float* out = (float*)d_out;

    const int Bb = B_ROWS, Dd = D_DIM;

    char* w = (char*)d_ws;
    size_t off = 0;
    auto carve = [&](size_t bytes) {
        void* p = w + off;
        off += (bytes + 255) & ~(size_t)255;
        return p;
    };
    half_t* xh  = (half_t*)carve((size_t)Bb * Dd * 2);
    half_t* Wqh = (half_t*)carve((size_t)Dd * Dd * 2);
    half_t* Wkh = (half_t*)carve((size_t)Dd * Dd * 2);
    half_t* Wvh = (half_t*)carve((size_t)Dd * Dd * 2);
    half_t* Qh  = (half_t*)carve((size_t)Bb * Dd * 2);
    half_t* Kh  = (half_t*)carve((size_t)Bb * Dd * 2);
    half_t* Vh  = (half_t*)carve((size_t)Bb * Dd * 2);
    half_t* S   = (half_t*)carve((size_t)Bb * Bb * 2);
    half_t* Vt  = xh;                 // xh dead after projections
    float*  part1 = (float*)Qh;       // Qh+Kh dead after QK^T

    // 1) converts
    cvt_f32_f16<<<2048, 256, 0, stream>>>(x,  xh,  Bb * Dd);
    cvt_f32_f16<<<1024, 256, 0, stream>>>(Wq, Wqh, Dd * Dd);
    cvt_f32_f16<<<1024, 256, 0, stream>>>(Wk, Wkh, Dd * Dd);
    cvt_f32_f16<<<1024, 256, 0, stream>>>(Wv, Wvh, Dd * Dd);

    // 2) fused QKV projections
    dim3 gqkv(Dd / 256, Bb / 256, 3);
    gemm8_qkv<<<gqkv, 512, 0, stream>>>(xh, Wqh, Wkh, Wvh, bq, bk, bv, Qh, Kh, Vh);

    // 3) V -> V^T
    transpose_h<<<(Dd / 64) * (Bb / 64), 256, 0, stream>>>(Vh, Vt, Bb, Dd);

    // 4) S = 0.125 * Q K^T
    dim3 gs(Bb / 256, Bb / 256);
    gemm8<1><<<gs, 512, 0, stream>>>(Qh, Kh, nullptr, S, Dd, Dd, Bb, 0.125f, Dd / 64);

    // 5) row softmax in place
    softmax_rows<<<Bb, 256, 0, stream>>>(S, Bb);

    // 6) O = P Vt^T, split-K=2, then reduce partials
    dim3 gpv(Dd / 256, Bb / 256, 2);
    gemm8_pv<<<gpv, 512, 0, stream>>>(S, Vt, out, part1);
    add_f32<<<2048, 256, 0, stream>>>(part1, out, Bb * Dd);
}

// Round 4
// 434.592 us; speedup vs baseline: 1.0913x; 1.0913x over previous
//
#include <hip/hip_runtime.h>
#include <hip/hip_bf16.h>

typedef _Float16 half_t;
typedef _Float16 f16x8 __attribute__((ext_vector_type(8)));
typedef _Float16 f16x4 __attribute__((ext_vector_type(4)));
typedef float f32x4 __attribute__((ext_vector_type(4)));

#define B_ROWS 8192
#define D_DIM  1024

__device__ __forceinline__ void gload_lds16(const void* g, void* l)
{
    __builtin_amdgcn_global_load_lds((const __attribute__((address_space(1))) void*)g,
                                     (__attribute__((address_space(3))) void*)l, 16, 0, 0);
}

// ---------------------------------------------------------------------------
// f32 -> f16 convert
// ---------------------------------------------------------------------------
__global__ __launch_bounds__(256)
void cvt_f32_f16(const float* __restrict__ in, half_t* __restrict__ out, int n)
{
    int i = (blockIdx.x * 256 + threadIdx.x) * 4;
    int stride = gridDim.x * 256 * 4;
    for (; i < n; i += stride) {
        float4 v = *(const float4*)&in[i];
        f16x4 o;
        o[0] = (half_t)v.x; o[1] = (half_t)v.y; o[2] = (half_t)v.z; o[3] = (half_t)v.w;
        *(f16x4*)&out[i] = o;
    }
}

// ---------------------------------------------------------------------------
// LDS-tiled transpose (64x64 tiles, +1 pad)
// ---------------------------------------------------------------------------
__global__ __launch_bounds__(256)
void transpose_h(const half_t* __restrict__ in, half_t* __restrict__ out, int R, int C)
{
    __shared__ half_t t[64][65];
    int tilesC = C >> 6;
    int bc = blockIdx.x % tilesC;
    int br = blockIdx.x / tilesC;
    int r0 = br * 64, c0 = bc * 64;
    for (int e = threadIdx.x; e < 64 * 64; e += 256) {
        int r = e >> 6, c = e & 63;
        t[r][c] = in[(size_t)(r0 + r) * C + (c0 + c)];
    }
    __syncthreads();
    for (int e = threadIdx.x; e < 64 * 64; e += 256) {
        int r = e >> 6, c = e & 63;
        out[(size_t)(c0 + r) * R + (r0 + c)] = t[c][r];
    }
}

// ---------------------------------------------------------------------------
// 256x256 8-phase NT GEMM core (round-2 structure, measured 800 TF).
//   C[i,j] = scale * sum_k A[i,k]*B[j,k] (+bias[j])
// 512 threads = 8 waves (2Mx4N). LDS 128 KiB (2 dbuf x 2 halves x A,B).
// Swizzle: byte ^= (row&7)<<4 (read side); inverse-swizzled global source.
// Per K-tile t, 4 phases; each: reads|stage -> bar -> setprio(1) 16 MFMA
// setprio(0) -> bar ; one counted vmcnt(4) gate per K-tile (end of phase 4).
// ---------------------------------------------------------------------------
template<int EPI>
__device__ __forceinline__ void gemm8_core(
    const half_t* __restrict__ A, const half_t* __restrict__ Bm,
    const float* __restrict__ bias, void* __restrict__ Out,
    int lda, int ldb, int ldc, float scale,
    int row0, int col0, int ktile0, int nkt)
{
    __shared__ __align__(16) half_t As[4 * 8192];
    __shared__ __align__(16) half_t Bs[4 * 8192];

    const int tid  = threadIdx.x;
    const int lane = tid & 63;
    const int wid  = tid >> 6;
    const int wr   = wid >> 2;     // 0..1  (M)
    const int wcn  = wid & 3;      // 0..3  (N)
    const int l15  = lane & 15;
    const int l4   = lane >> 4;

    // staging: linear LDS dest (tid*16), inverse-swizzled global source slot
    const int trow  = tid >> 3;                       // 0..63
    const int tslot = (tid & 7) ^ (trow & 7);
    const char* Apan[2] = { (const char*)(A + (size_t)row0 * lda),
                            (const char*)(A + (size_t)(row0 + 128) * lda) };
    const char* Bpan[2] = { (const char*)(Bm + (size_t)col0 * ldb),
                            (const char*)(Bm + (size_t)(col0 + 128) * ldb) };
    const size_t aoff[2] = { (size_t)trow * lda * 2 + (size_t)tslot * 16,
                             (size_t)(trow + 64) * lda * 2 + (size_t)tslot * 16 };
    const size_t boff[2] = { (size_t)trow * ldb * 2 + (size_t)tslot * 16,
                             (size_t)(trow + 64) * ldb * 2 + (size_t)tslot * 16 };
    const int dstb[2] = { tid * 16, 8192 + tid * 16 };

    auto stageA = [&](int h, int s, int buf) {
        char* d = (char*)(As + (buf * 2 + h) * 8192);
        const char* g = Apan[h] + (size_t)(ktile0 + s) * 128;
        gload_lds16(g + aoff[0], d + dstb[0]);
        gload_lds16(g + aoff[1], d + dstb[1]);
    };
    auto stageB = [&](int h, int s, int buf) {
        char* d = (char*)(Bs + (buf * 2 + h) * 8192);
        const char* g = Bpan[h] + (size_t)(ktile0 + s) * 128;
        gload_lds16(g + boff[0], d + dstb[0]);
        gload_lds16(g + boff[1], d + dstb[1]);
    };
    // swizzled fragment reads (rih&7 spreads banks)
    auto rdA = [&](int mm, int kb, const half_t* base) -> f16x8 {
        int rih  = mm * 32 + wr * 16 + l15;
        int byte = rih * 128 + (((kb * 4 + l4) ^ (rih & 7)) << 4);
        return *(const f16x8*)((const char*)base + byte);
    };
    auto rdB = [&](int nn, int kb, const half_t* base) -> f16x8 {
        int rih  = nn * 64 + wcn * 16 + l15;
        int byte = rih * 128 + (((kb * 4 + l4) ^ (rih & 7)) << 4);
        return *(const f16x8*)((const char*)base + byte);
    };

    f32x4 acc[8][4] = {};
    f16x8 af[2][4], bf[2][2];

    // prologue: stage K-tile 0 fully + A0/B0 of tile 1; gate so tile 0 landed
    {
        int s1 = (nkt > 1) ? 1 : 0;
        stageA(0, 0, 0); stageB(0, 0, 0); stageA(1, 0, 0); stageB(1, 0, 0);
        stageA(0, s1, 1); stageB(0, s1, 1);
    }
    asm volatile("s_waitcnt vmcnt(4)" ::: "memory");
    asm volatile("s_barrier" ::: "memory");

    for (int t = 0; t < nkt; ++t) {
        const int buf = t & 1;
        const half_t* A0 = As + (buf * 2 + 0) * 8192;
        const half_t* A1 = As + (buf * 2 + 1) * 8192;
        const half_t* B0 = Bs + (buf * 2 + 0) * 8192;
        const half_t* B1 = Bs + (buf * 2 + 1) * 8192;
        int t1  = t + 1; int t1s = (t1 < nkt) ? t1 : nkt - 1; int b1 = t1 & 1;
        int t2  = t + 2; int t2s = (t2 < nkt) ? t2 : nkt - 1;

        // ---- phase 1: quadrant (m0-3, n0-1)
        #pragma unroll
        for (int m = 0; m < 4; ++m) { af[0][m] = rdA(m, 0, A0); af[1][m] = rdA(m, 1, A0); }
        #pragma unroll
        for (int n = 0; n < 2; ++n) { bf[0][n] = rdB(n, 0, B0); bf[1][n] = rdB(n, 1, B0); }
        stageA(1, t1s, b1);
        asm volatile("s_barrier" ::: "memory");
        __builtin_amdgcn_s_setprio(1);
        #pragma unroll
        for (int kb = 0; kb < 2; ++kb)
            #pragma unroll
            for (int m = 0; m < 4; ++m)
                #pragma unroll
                for (int n = 0; n < 2; ++n)
                    acc[m][n] = __builtin_amdgcn_mfma_f32_16x16x32_f16(af[kb][m], bf[kb][n], acc[m][n], 0, 0, 0);
        __builtin_amdgcn_s_setprio(0);
        asm volatile("s_barrier" ::: "memory");

        // ---- phase 2: quadrant (m0-3, n2-3)
        #pragma unroll
        for (int n = 0; n < 2; ++n) { bf[0][n] = rdB(n, 0, B1); bf[1][n] = rdB(n, 1, B1); }
        stageB(1, t1s, b1);
        asm volatile("s_barrier" ::: "memory");
        __builtin_amdgcn_s_setprio(1);
        #pragma unroll
        for (int kb = 0; kb < 2; ++kb)
            #pragma unroll
            for (int m = 0; m < 4; ++m)
                #pragma unroll
                for (int n = 0; n < 2; ++n)
                    acc[m][n + 2] = __builtin_amdgcn_mfma_f32_16x16x32_f16(af[kb][m], bf[kb][n], acc[m][n + 2], 0, 0, 0);
        __builtin_amdgcn_s_setprio(0);
        asm volatile("s_barrier" ::: "memory");

        // ---- phase 3: quadrant (m4-7, n0-1)
        #pragma unroll
        for (int m = 0; m < 4; ++m) { af[0][m] = rdA(m, 0, A1); af[1][m] = rdA(m, 1, A1); }
        #pragma unroll
        for (int n = 0; n < 2; ++n) { bf[0][n] = rdB(n, 0, B0); bf[1][n] = rdB(n, 1, B0); }
        stageA(0, t2s, buf);
        asm volatile("s_barrier" ::: "memory");
        __builtin_amdgcn_s_setprio(1);
        #pragma unroll
        for (int kb = 0; kb < 2; ++kb)
            #pragma unroll
            for (int m = 0; m < 4; ++m)
                #pragma unroll
                for (int n = 0; n < 2; ++n)
                    acc[m + 4][n] = __builtin_amdgcn_mfma_f32_16x16x32_f16(af[kb][m], bf[kb][n], acc[m + 4][n], 0, 0, 0);
        __builtin_amdgcn_s_setprio(0);
        asm volatile("s_barrier" ::: "memory");

        // ---- phase 4: quadrant (m4-7, n2-3)
        #pragma unroll
        for (int n = 0; n < 2; ++n) { bf[0][n] = rdB(n, 0, B1); bf[1][n] = rdB(n, 1, B1); }
        stageB(0, t2s, buf);
        asm volatile("s_barrier" ::: "memory");
        __builtin_amdgcn_s_setprio(1);
        #pragma unroll
        for (int kb = 0; kb < 2; ++kb)
            #pragma unroll
            for (int m = 0; m < 4; ++m)
                #pragma unroll
                for (int n = 0; n < 2; ++n)
                    acc[m + 4][n + 2] = __builtin_amdgcn_mfma_f32_16x16x32_f16(af[kb][m], bf[kb][n], acc[m + 4][n + 2], 0, 0, 0);
        __builtin_amdgcn_s_setprio(0);
        asm volatile("s_waitcnt vmcnt(4)" ::: "memory");   // counted gate: next tile landed
        asm volatile("s_barrier" ::: "memory");
    }

    // epilogue: C/D layout col = l15, row = l4*4 + r
    #pragma unroll
    for (int m = 0; m < 8; ++m) {
        int grow_base = row0 + m * 32 + wr * 16 + l4 * 4;
        #pragma unroll
        for (int n = 0; n < 4; ++n) {
            int gcol = col0 + n * 64 + wcn * 16 + l15;
            float badd = (EPI == 0) ? bias[gcol] : 0.0f;
            #pragma unroll
            for (int r = 0; r < 4; ++r) {
                float v = acc[m][n][r] * scale + badd;
                size_t idx = (size_t)(grow_base + r) * ldc + gcol;
                if (EPI == 2) ((float*)Out)[idx] = v;
                else          ((half_t*)Out)[idx] = (half_t)v;
            }
        }
    }
}

// wrapper. REMAP=1: 16x16 supertile + XCD-chunked 2x16 slabs (requires 32x32 grid).
// REMAP=0: plain XCD swizzle.
template<int EPI, int REMAP>
__global__ __launch_bounds__(512, 2)
void gemm8(const half_t* __restrict__ A, const half_t* __restrict__ Bm,
           const float* __restrict__ bias, void* __restrict__ Out,
           int lda, int ldb, int ldc, float scale, int nkt)
{
    int bx, by;
    if (REMAP) {
        // linear dispatch id -> supertile 16x16 of (Qpanel x Kpanel), XCD-chunked
        int L = blockIdx.y * gridDim.x + blockIdx.x;   // 0..1023
        int s = L >> 8;            // supertile 0..3 (2x2 of 16x16)
        int u = L & 255;
        int xcd  = u & 7;          // consecutive ids round-robin XCDs
        int slot = u >> 3;         // 0..31 within XCD: 2 rows x 16 cols
        by = (s >> 1) * 16 + xcd * 2 + (slot >> 4);
        bx = (s & 1) * 16 + (slot & 15);
    } else {
        int nwg = gridDim.x * gridDim.y;
        int bid = blockIdx.y * gridDim.x + blockIdx.x;
        if ((nwg & 7) == 0) { int c = nwg >> 3; bid = (bid & 7) * c + (bid >> 3); }
        bx = bid % gridDim.x; by = bid / gridDim.x;
    }
    gemm8_core<EPI>(A, Bm, bias, Out, lda, ldb, ldc, scale, by * 256, bx * 256, 0, nkt);
}

// fused QKV projections: z picks (W, b, Out)
__global__ __launch_bounds__(512, 2)
void gemm8_qkv(const half_t* __restrict__ xh,
               const half_t* __restrict__ Wq, const half_t* __restrict__ Wk, const half_t* __restrict__ Wv,
               const float* __restrict__ bq, const float* __restrict__ bk, const float* __restrict__ bv,
               half_t* __restrict__ Q, half_t* __restrict__ K, half_t* __restrict__ V)
{
    int z = blockIdx.z;
    const half_t* W = (z == 0) ? Wq : (z == 1) ? Wk : Wv;
    const float*  b = (z == 0) ? bq : (z == 1) ? bk : bv;
    half_t*       O = (z == 0) ? Q  : (z == 1) ? K  : V;
    gemm8_core<0>(xh, W, b, O, D_DIM, D_DIM, D_DIM, 1.0f,
                  blockIdx.y * 256, blockIdx.x * 256, 0, D_DIM / 64);
}

// PV with split-K=2: z=0 -> part0 (d_out), z=1 -> part1 (ws)
__global__ __launch_bounds__(512, 2)
void gemm8_pv(const half_t* __restrict__ S, const half_t* __restrict__ Vt,
              float* __restrict__ part0, float* __restrict__ part1)
{
    int z = blockIdx.z;
    float* O = z ? part1 : part0;
    gemm8_core<2>(S, Vt, nullptr, O, B_ROWS, B_ROWS, D_DIM, 1.0f,
                  blockIdx.y * 256, blockIdx.x * 256, z * (B_ROWS / 128), B_ROWS / 128);
}

// out += a
__global__ __launch_bounds__(256)
void add_f32(const float* __restrict__ a, float* __restrict__ out, int n)
{
    int i = (blockIdx.x * 256 + threadIdx.x) * 4;
    int stride = gridDim.x * 256 * 4;
    for (; i < n; i += stride) {
        float4 x = *(const float4*)&out[i];
        float4 y = *(const float4*)&a[i];
        x.x += y.x; x.y += y.y; x.z += y.z; x.w += y.w;
        *(float4*)&out[i] = x;
    }
}

// ---------------------------------------------------------------------------
// Row softmax in place on fp16 [8192 x 8192]
// ---------------------------------------------------------------------------
__global__ __launch_bounds__(256)
void softmax_rows(half_t* __restrict__ S, int ncol)
{
    const int row = blockIdx.x;
    half_t* srow = S + (size_t)row * ncol;
    const int tid = threadIdx.x;

    float ev[32];
    float m = -1e30f;
    #pragma unroll
    for (int it = 0; it < 4; ++it) {
        int j = it * 2048 + tid * 8;
        f16x8 v = *(const f16x8*)&srow[j];
        #pragma unroll
        for (int t = 0; t < 8; ++t) {
            float f = (float)v[t];
            ev[it * 8 + t] = f;
            m = fmaxf(m, f);
        }
    }
    #pragma unroll
    for (int o = 32; o; o >>= 1) m = fmaxf(m, __shfl_down(m, o));
    __shared__ float redm[8];
    __shared__ float reds[8];
    if ((tid & 63) == 0) redm[tid >> 6] = m;
    __syncthreads();
    m = fmaxf(fmaxf(redm[0], redm[1]), fmaxf(redm[2], redm[3]));

    float s = 0.0f;
    #pragma unroll
    for (int e = 0; e < 32; ++e) {
        float ex = __expf(ev[e] - m);
        ev[e] = ex;
        s += ex;
    }
    #pragma unroll
    for (int o = 32; o; o >>= 1) s += __shfl_down(s, o);
    if ((tid & 63) == 0) reds[tid >> 6] = s;
    __syncthreads();
    s = reds[0] + reds[1] + reds[2] + reds[3];
    float inv = 1.0f / s;

    #pragma unroll
    for (int it = 0; it < 4; ++it) {
        int j = it * 2048 + tid * 8;
        f16x8 o8;
        #pragma unroll
        for (int t = 0; t < 8; ++t) o8[t] = (half_t)(ev[it * 8 + t] * inv);
        *(f16x8*)&srow[j] = o8;
    }
}

// ---------------------------------------------------------------------------
// launcher
// ---------------------------------------------------------------------------
extern "C" void kernel_launch(void* const* d_in, const int* in_sizes, int n_in,
                              void* d_out, int out_size, void* d_ws, size_t ws_size,
                              hipStream_t stream)
{
    const float* x  = (const float*)d_in[0];
    const float* Wq = (const float*)d_in[1];
    const float* bq = (const float*)d_in[2];
    const float* Wk = (const float*)d_in[3];
    const float* bk = (const float*)d_in[4];
    const float* Wv = (const float*)d_in[5];
    const float* bv = (const float*)d_in[6];
    float* out = (float*)d_out;

    const int Bb = B_ROWS, Dd = D_DIM;

    char* w = (char*)d_ws;
    size_t off = 0;
    auto carve = [&](size_t bytes) {
        void* p = w + off;
        off += (bytes + 255) & ~(size_t)255;
        return p;
    };
    half_t* xh  = (half_t*)carve((size_t)Bb * Dd * 2);
    half_t* Wqh = (half_t*)carve((size_t)Dd * Dd * 2);
    half_t* Wkh = (half_t*)carve((size_t)Dd * Dd * 2);
    half_t* Wvh = (half_t*)carve((size_t)Dd * Dd * 2);
    half_t* Qh  = (half_t*)carve((size_t)Bb * Dd * 2);
    half_t* Kh  = (half_t*)carve((size_t)Bb * Dd * 2);
    half_t* Vh  = (half_t*)carve((size_t)Bb * Dd * 2);
    half_t* S   = (half_t*)carve((size_t)Bb * Bb * 2);
    half_t* Vt  = xh;                 // xh dead after projections
    float*  part1 = (float*)Qh;       // Qh+Kh dead after QK^T

    // 1) converts
    cvt_f32_f16<<<2048, 256, 0, stream>>>(x,  xh,  Bb * Dd);
    cvt_f32_f16<<<1024, 256, 0, stream>>>(Wq, Wqh, Dd * Dd);
    cvt_f32_f16<<<1024, 256, 0, stream>>>(Wk, Wkh, Dd * Dd);
    cvt_f32_f16<<<1024, 256, 0, stream>>>(Wv, Wvh, Dd * Dd);

    // 2) fused QKV projections
    dim3 gqkv(Dd / 256, Bb / 256, 3);
    gemm8_qkv<<<gqkv, 512, 0, stream>>>(xh, Wqh, Wkh, Wvh, bq, bk, bv, Qh, Kh, Vh);

    // 3) V -> V^T
    transpose_h<<<(Dd / 64) * (Bb / 64), 256, 0, stream>>>(Vh, Vt, Bb, Dd);

    // 4) S = 0.125 * Q K^T  (supertile-remapped grid for L2/L3 panel reuse)
    dim3 gs(Bb / 256, Bb / 256);
    gemm8<1, 1><<<gs, 512, 0, stream>>>(Qh, Kh, nullptr, S, Dd, Dd, Bb, 0.125f, Dd / 64);

    // 5) row softmax in place
    softmax_rows<<<Bb, 256, 0, stream>>>(S, Bb);

    // 6) O = P Vt^T, split-K=2, then reduce partials
    dim3 gpv(Dd / 256, Bb / 256, 2);
    gemm8_pv<<<gpv, 512, 0, stream>>>(S, Vt, out, part1);
    add_f32<<<2048, 256, 0, stream>>>(part1, out, Bb * Dd);
}